// Round 15
// baseline (24.745 us; speedup 1.0000x reference)
//
#include <hip/hip_runtime.h>
#include <hip/hip_bf16.h>

typedef short short8 __attribute__((ext_vector_type(8)));
typedef float f32x4 __attribute__((ext_vector_type(4)));

union FragAB { unsigned long long l[2]; int i[4]; short8 v; };

// Round-15: prep kernel converts x once into fragment-tiled bf16
// xTf[sx][kb=k/8][p=b*16+f][e=k%8] in d_ws (1 MB, L2-resident); the main
// kernel loads A-fragments DIRECTLY from global (1 b128 per m per K-step,
// 4x256B segments per wave) — no 64 KB LDS staging, no cvts, no big barrier.
//
// Swapped-operand formulation: D[p=(b,f), j] = sum_i A[p,i] * B[i,j]
//   B[i,j] = T[j,i] = wfor[255 + diag - j + i]
//   wfor[q] = krow[q] for q in [0,255], 0 elsewhere (zero-pad = triangular
//   mask AND the diagonal roll-by-one, which switches divisor to j+1-diag).
// Copy s holds wfor shifted +s; reads use byte = s*674 + 2*w00 -> every
// lane's 8-element window is 8-byte aligned (2x ds_read_b64).

// ---- prep: x [16,8,256,16] fp32 -> xTf [sx][kb][p][8] bf16 ----
__global__ __launch_bounds__(256)
void k_prep(const float* __restrict__ x, ushort* __restrict__ xTf)
{
    __shared__ float xs[256 * 17];          // [k][f] padded
    const int blk = blockIdx.x;             // 0..127
    const int b = blk >> 3, sx = blk & 7;
    const int t = threadIdx.x;

    const float4* src = reinterpret_cast<const float4*>(x + (b * 8 + sx) * 4096);
    #pragma unroll
    for (int it = 0; it < 4; ++it) {
        int id = it * 256 + t;              // float4 id 0..1023
        float4 v = src[id];
        int k = id >> 2, fq = (id & 3) * 4;
        xs[k * 17 + fq + 0] = v.x;
        xs[k * 17 + fq + 1] = v.y;
        xs[k * 17 + fq + 2] = v.z;
        xs[k * 17 + fq + 3] = v.w;
    }
    __syncthreads();

    const int f = t >> 4, kh = t & 15;      // kh: 16-k chunk
    #pragma unroll
    for (int d = 0; d < 2; ++d) {
        const int kb = 2 * kh + d;          // 8-k block 0..31
        uint u[4];
        #pragma unroll
        for (int i = 0; i < 4; ++i) {
            float v0 = xs[(kb * 8 + 2 * i) * 17 + f];
            float v1 = xs[(kb * 8 + 2 * i + 1) * 17 + f];
            __hip_bfloat16 h0 = __float2bfloat16(v0);
            __hip_bfloat16 h1 = __float2bfloat16(v1);
            u[i] = (uint)reinterpret_cast<ushort&>(h0) |
                   ((uint)reinterpret_cast<ushort&>(h1) << 16);
        }
        int4* dst = reinterpret_cast<int4*>(
            xTf + ((size_t)(sx * 32 + kb) * 256 + b * 16 + f) * 8);
        *dst = make_int4((int)u[0], (int)u[1], (int)u[2], (int)u[3]);
    }
}

// ---- main: R13 wave structure, A-frags from global xTf ----
__global__ __launch_bounds__(256)
void k_main(const ushort* __restrict__ xTf,  // [sx][kb][p][8] bf16
            const float* __restrict__ kern,  // [4,8,8,256]
            float* __restrict__ out)         // [16,4,8,8,256,16]
{
    __shared__ __align__(8) ushort wforL[4][336];   // [shift][q]
    __shared__ float rtab[256];

    const int blk = blockIdx.x;             // 0..1023
    const int hy = blk & 31;                // h*8 + sy
    const int sx = (blk >> 5) & 7;
    const int nt = blk >> 8;                // p-quarter (b-quad)
    const int h = hy >> 3, sy = hy & 7;
    const int diag = (sx == sy) ? 1 : 0;
    const int t = threadIdx.x;

    // ---- minimal wfor build: 1 load, 1 cvt, 4 shifted stores, zero tails --
    {
        const float* krow = kern + ((h * 8 + sx) * 8 + sy) * 256;
        float v = krow[t];
        __hip_bfloat16 hv = __float2bfloat16(v);
        ushort u = reinterpret_cast<ushort&>(hv);
        #pragma unroll
        for (int s = 0; s < 4; ++s)
            wforL[s][t + s] = u;                 // wforL[s][q] = wfor[q-s]
        if (t < 88) {                            // zero tail q in [256+s, 336)
            #pragma unroll
            for (int s = 0; s < 4; ++s) {
                int q = 256 + s + t;
                if (q < 336) wforL[s][q] = 0;
            }
        }
        if (t < 4) {                             // zero head q in [0, s)
            #pragma unroll
            for (int s = 1; s < 4; ++s)
                if (t < s) wforL[s][t] = 0;
        }
        int denom = t + 1 - diag;
        rtab[t] = (denom > 0) ? (1.0f / (float)denom) : 0.0f;
    }
    __syncthreads();

    const int lane = t & 63, wid = t >> 6;
    const int laneM = lane & 15, laneG = lane >> 4;
    const int wj0 = wid * 64;                   // wave's j base
    const int kmax = wj0 + 64;                  // triangle skip

    const char* WB = reinterpret_cast<const char*>(wforL);
    // A-frag (m, kc): 16B at xTf[(sx*32 + kc/8 + laneG)*256 + nt*64+16m+laneM]
    const ushort* agbase = xTf + ((size_t)(sx * 32 + laneG) * 256
                                  + nt * 64 + laneM) * 8;

    // B element e (lane) for frag n, step kc: wfor[w00 + kc - 16n + e]
    const int w00 = 255 + diag - wj0 - laneM + 8 * laneG;
    const int s = (laneM - diag + 1) & 3;       // makes (w00+s) % 4 == 0
    const int bB = s * 674 + 2 * w00;           // byte base (incl. +s shift)

    f32x4 acc[4][4];
    #pragma unroll
    for (int m = 0; m < 4; ++m)
        #pragma unroll
        for (int n = 0; n < 4; ++n)
            acc[m][n] = (f32x4){0.0f, 0.0f, 0.0f, 0.0f};

    for (int kc = 0; kc < kmax; kc += 32) {
        FragAB af[4];
        #pragma unroll
        for (int m = 0; m < 4; ++m) {
            const int4 raw = *reinterpret_cast<const int4*>(
                agbase + ((size_t)(kc >> 3) * 256 + 16 * m) * 8);
            af[m].i[0] = raw.x; af[m].i[1] = raw.y;
            af[m].i[2] = raw.z; af[m].i[3] = raw.w;
        }
        FragAB bf[4];
        #pragma unroll
        for (int n = 0; n < 4; ++n) {
            const char* p = WB + bB + kc * 2 - 32 * n;
            bf[n].l[0] = *reinterpret_cast<const unsigned long long*>(p);
            bf[n].l[1] = *reinterpret_cast<const unsigned long long*>(p + 8);
        }
        #pragma unroll
        for (int m = 0; m < 4; ++m)
            #pragma unroll
            for (int n = 0; n < 4; ++n)
                acc[m][n] = __builtin_amdgcn_mfma_f32_16x16x32_bf16(
                    af[m].v, bf[n].v, acc[m][n], 0, 0, 0);
    }

    // ---- epilogue: scale rows, nontemporal float4 stores ----
    #pragma unroll
    for (int m = 0; m < 4; ++m) {
        const int b_ = nt * 4 + m;
        float* obase = out + (((size_t)(b_ * 4 + h) * 8 + sx) * 8 + sy) * 4096
                       + laneG * 4;
        #pragma unroll
        for (int n = 0; n < 4; ++n) {
            const int j = wj0 + 16 * n + laneM;
            const float rt = rtab[j];
            f32x4 v = acc[m][n] * rt;
            __builtin_nontemporal_store(
                v, reinterpret_cast<f32x4*>(obase + (size_t)j * 16));
        }
    }
}

extern "C" void kernel_launch(void* const* d_in, const int* in_sizes, int n_in,
                              void* d_out, int out_size, void* d_ws, size_t ws_size,
                              hipStream_t stream) {
    const float* x    = (const float*)d_in[0];   // [16,8,256,16]
    const float* kern = (const float*)d_in[1];   // [4,8,8,256]
    float* out = (float*)d_out;                  // [16,4,8,8,256,16]
    ushort* xTf = (ushort*)d_ws;                 // 1 MB bf16 scratch

    k_prep<<<128, 256, 0, stream>>>(x, xTf);
    k_main<<<1024, 256, 0, stream>>>(xTf, kern, out);
}

// Round 16
// 20.188 us; speedup vs baseline: 1.2258x; 1.2258x over previous
//
#include <hip/hip_runtime.h>
#include <hip/hip_bf16.h>

typedef short short8 __attribute__((ext_vector_type(8)));
typedef float f32x4 __attribute__((ext_vector_type(4)));

union FragAB { unsigned long long l[2]; int i[4]; short8 v; };

template<int N> struct IC { static constexpr int value = N; };

// Round-16 = round-13 base (best, 19.70 us) + two K-loop scheduling fixes:
//  1) band = (wid + blk) & 3: with 3 resident blocks/CU, each SIMD hosts a
//     {light,mid,heavy} band mix (12-18 K-steps) instead of 3x the same band
//     (6 vs 24 steps) -> shorter per-CU critical path.
//  2) switch(band) -> compile-time trip counts (2/4/6/8), fully unrolled ->
//     compiler batches independent ds_reads across K-steps (hides ~120cyc
//     LDS latency) instead of iterating a runtime-bound loop.
//
// Swapped-operand formulation: D[p=(b,f), j] = sum_i A[p,i] * B[i,j]
//   A[p,i] = bf16(x[b, sx, i, f])            (Xts rows, k-contiguous)
//   B[i,j] = T[j,i] = wfor[255 + diag - j + i]
//   wfor[q] = krow[q] for q in [0,255], 0 elsewhere (zero-pad = triangular
//   mask AND the diagonal roll-by-one, which switches divisor to j+1-diag).
// Copy s holds wfor shifted +s (wforL[s][q] = wfor[q-s]); reads use
// byte = s*674 + 2*w00 -> every lane's 8-element window is 8-byte aligned.
__global__ __launch_bounds__(256, 3)
void k_fused(const float* __restrict__ x,     // [16,8,256,16]
             const float* __restrict__ kern,  // [4,8,8,256]
             float* __restrict__ out)         // [16,4,8,8,256,16]
{
    __shared__ __align__(16) ushort Xts[64 * 264];   // [p][k], row 528 B
    __shared__ __align__(8)  ushort wforL[4][336];   // [shift][q]
    __shared__ float rtab[256];

    const int blk = blockIdx.x;             // 0..1023
    const int hy = blk & 31;                // h*8 + sy
    const int sx = (blk >> 5) & 7;
    const int nt = blk >> 8;                // p-quarter (b-quad)
    const int h = hy >> 3, sy = hy & 7;
    const int diag = (sx == sy) ? 1 : 0;
    const int t = threadIdx.x;

    // ---- minimal wfor build: 1 load, 1 cvt, 4 shifted stores, zero tails --
    {
        const float* krow = kern + ((h * 8 + sx) * 8 + sy) * 256;
        float v = krow[t];
        __hip_bfloat16 hv = __float2bfloat16(v);
        ushort u = reinterpret_cast<ushort&>(hv);
        #pragma unroll
        for (int s = 0; s < 4; ++s)
            wforL[s][t + s] = u;                 // wforL[s][q] = wfor[q-s]
        if (t < 88) {                            // zero tail q in [256+s, 336)
            #pragma unroll
            for (int s = 0; s < 4; ++s) {
                int q = 256 + s + t;
                if (q < 336) wforL[s][q] = 0;
            }
        }
        if (t < 4) {                             // zero head q in [0, s)
            #pragma unroll
            for (int s = 1; s < 4; ++s)
                if (t < s) wforL[s][t] = 0;
        }
    }
    // ---- reciprocal table for this block's diag ----
    {
        int denom = t + 1 - diag;
        rtab[t] = (denom > 0) ? (1.0f / (float)denom) : 0.0f;
    }
    // ---- stage + transpose x quarter-slice -> Xts: Xts[bl*16+f][k] ----
    {
        const float4* xbase = reinterpret_cast<const float4*>(x);
        #pragma unroll
        for (int it = 0; it < 8; ++it) {
            int id = it * 256 + t;              // 0..2047
            int fq = id & 3;
            int k2 = (id >> 2) & 127;
            int bl = id >> 9;                   // local b 0..3
            const float4* rowp = xbase + ((size_t)((nt * 4 + bl) * 8 + sx)) * 1024;
            float4 a = rowp[(2 * k2) * 4 + fq];
            float4 cq = rowp[(2 * k2 + 1) * 4 + fq];
            #pragma unroll
            for (int e = 0; e < 4; ++e) {
                float va = (&a.x)[e], vb = (&cq.x)[e];
                __hip_bfloat16 ha = __float2bfloat16(va);
                __hip_bfloat16 hb = __float2bfloat16(vb);
                uint u = (uint)reinterpret_cast<ushort&>(ha) |
                         ((uint)reinterpret_cast<ushort&>(hb) << 16);
                int row = bl * 16 + fq * 4 + e;
                *reinterpret_cast<uint*>(reinterpret_cast<char*>(Xts) + row * 528 + k2 * 4) = u;
            }
        }
    }
    __syncthreads();

    const int lane = t & 63, wid = t >> 6;
    const int laneM = lane & 15, laneG = lane >> 4;
    const int band = (wid + blk) & 3;           // SIMD-balanced j-band
    const int wj0 = band * 64;                  // wave's j base

    const char* XtsB = reinterpret_cast<const char*>(Xts);
    const char* WB = reinterpret_cast<const char*>(wforL);
    const int abyte = laneM * 528 + laneG * 16;

    // B element e (lane) for frag n, step kc: wfor[w00 + kc - 16n + e]
    const int w00 = 255 + diag - wj0 - laneM + 8 * laneG;
    const int s = (laneM - diag + 1) & 3;       // makes (w00+s) % 4 == 0
    const int bB = s * 674 + 2 * w00;           // byte base (incl. +s shift)

    f32x4 acc[4][4];
    #pragma unroll
    for (int m = 0; m < 4; ++m)
        #pragma unroll
        for (int n = 0; n < 4; ++n)
            acc[m][n] = (f32x4){0.0f, 0.0f, 0.0f, 0.0f};

    auto kloop = [&](auto NSTEP) {
        #pragma unroll
        for (int st = 0; st < decltype(NSTEP)::value; ++st) {
            const int kc = 32 * st;
            FragAB af[4];
            #pragma unroll
            for (int m = 0; m < 4; ++m) {
                const int4 raw = *reinterpret_cast<const int4*>(
                    XtsB + abyte + m * 8448 + kc * 2);
                af[m].i[0] = raw.x; af[m].i[1] = raw.y;
                af[m].i[2] = raw.z; af[m].i[3] = raw.w;
            }
            FragAB bf[4];
            #pragma unroll
            for (int n = 0; n < 4; ++n) {
                const char* p = WB + bB + kc * 2 - 32 * n;
                bf[n].l[0] = *reinterpret_cast<const unsigned long long*>(p);
                bf[n].l[1] = *reinterpret_cast<const unsigned long long*>(p + 8);
            }
            #pragma unroll
            for (int m = 0; m < 4; ++m)
                #pragma unroll
                for (int n = 0; n < 4; ++n)
                    acc[m][n] = __builtin_amdgcn_mfma_f32_16x16x32_bf16(
                        af[m].v, bf[n].v, acc[m][n], 0, 0, 0);
        }
    };
    switch (band) {
        case 0:  kloop(IC<2>{}); break;
        case 1:  kloop(IC<4>{}); break;
        case 2:  kloop(IC<6>{}); break;
        default: kloop(IC<8>{}); break;
    }

    // ---- epilogue: scale rows, nontemporal float4 stores; m outer / n inner
    // so each m emits a 4 KB-contiguous run over n ----
    #pragma unroll
    for (int m = 0; m < 4; ++m) {
        const int b_ = nt * 4 + m;
        float* obase = out + (((size_t)(b_ * 4 + h) * 8 + sx) * 8 + sy) * 4096
                       + laneG * 4;
        #pragma unroll
        for (int n = 0; n < 4; ++n) {
            const int j = wj0 + 16 * n + laneM;
            const float rt = rtab[j];
            f32x4 v = acc[m][n] * rt;
            __builtin_nontemporal_store(
                v, reinterpret_cast<f32x4*>(obase + (size_t)j * 16));
        }
    }
}

extern "C" void kernel_launch(void* const* d_in, const int* in_sizes, int n_in,
                              void* d_out, int out_size, void* d_ws, size_t ws_size,
                              hipStream_t stream) {
    const float* x    = (const float*)d_in[0];   // [16,8,256,16]
    const float* kern = (const float*)d_in[1];   // [4,8,8,256]
    float* out = (float*)d_out;                  // [16,4,8,8,256,16]

    k_fused<<<1024, 256, 0, stream>>>(x, kern, out);
}

// Round 17
// 19.801 us; speedup vs baseline: 1.2497x; 1.0195x over previous
//
#include <hip/hip_runtime.h>
#include <hip/hip_bf16.h>

typedef short short8 __attribute__((ext_vector_type(8)));
typedef float f32x4 __attribute__((ext_vector_type(4)));

union FragAB { unsigned long long l[2]; int i[4]; short8 v; };

// FINAL (= round-13, best measured: 19.70 us).
//
// Swapped-operand formulation: D[p=(b,f), j] = sum_i A[p,i] * B[i,j]
//   A[p,i] = bf16(x[b, sx, i, f])            (Xts rows, k-contiguous)
//   B[i,j] = T[j,i] = wfor[255 + diag - j + i]
//   wfor[q] = krow[q] for q in [0,255], 0 elsewhere (zero-pad = triangular
//   mask AND the diagonal roll-by-one, which switches divisor to j+1-diag).
// Copy s holds wfor shifted +s (wforL[s][q] = wfor[q-s]); reads use
// byte = s*674 + 2*w00 (674 = 672 row stride + 2 for the +s element shift),
// making every lane's 8-element window 8-byte aligned -> 2x ds_read_b64.
//
// Block = (hy, sx, nt) computes a 64p x 256j tile; the 4 waves take the 4
// j-bands (kmax = 64*(wid+1)) -> identical total K-work per block; light
// waves' stores drain while heavy waves compute. LDS 37.5 KB, lb(256,3).
// Minimal wfor front-end (1 load + 1 cvt + 4 shifted stores per thread).
// Nontemporal float4 stores; m-outer/n-inner epilogue -> 4 KB runs.
__global__ __launch_bounds__(256, 3)
void k_fused(const float* __restrict__ x,     // [16,8,256,16]
             const float* __restrict__ kern,  // [4,8,8,256]
             float* __restrict__ out)         // [16,4,8,8,256,16]
{
    __shared__ __align__(16) ushort Xts[64 * 264];   // [p][k], row 528 B
    __shared__ __align__(8)  ushort wforL[4][336];   // [shift][q]
    __shared__ float rtab[256];

    const int blk = blockIdx.x;             // 0..1023
    const int hy = blk & 31;                // h*8 + sy
    const int sx = (blk >> 5) & 7;
    const int nt = blk >> 8;                // p-quarter (b-quad)
    const int h = hy >> 3, sy = hy & 7;
    const int diag = (sx == sy) ? 1 : 0;
    const int t = threadIdx.x;

    // ---- minimal wfor build: 1 load, 1 cvt, 4 shifted stores, zero tails --
    {
        const float* krow = kern + ((h * 8 + sx) * 8 + sy) * 256;
        float v = krow[t];
        __hip_bfloat16 hv = __float2bfloat16(v);
        ushort u = reinterpret_cast<ushort&>(hv);
        #pragma unroll
        for (int s = 0; s < 4; ++s)
            wforL[s][t + s] = u;                 // wforL[s][q] = wfor[q-s]
        if (t < 88) {                            // zero tail q in [256+s, 336)
            #pragma unroll
            for (int s = 0; s < 4; ++s) {
                int q = 256 + s + t;
                if (q < 336) wforL[s][q] = 0;
            }
        }
        if (t < 4) {                             // zero head q in [0, s)
            #pragma unroll
            for (int s = 1; s < 4; ++s)
                if (t < s) wforL[s][t] = 0;
        }
    }
    // ---- reciprocal table for this block's diag ----
    {
        int denom = t + 1 - diag;
        rtab[t] = (denom > 0) ? (1.0f / (float)denom) : 0.0f;
    }
    // ---- stage + transpose x quarter-slice -> Xts: Xts[bl*16+f][k] ----
    {
        const float4* xbase = reinterpret_cast<const float4*>(x);
        #pragma unroll
        for (int it = 0; it < 8; ++it) {
            int id = it * 256 + t;              // 0..2047
            int fq = id & 3;
            int k2 = (id >> 2) & 127;
            int bl = id >> 9;                   // local b 0..3
            const float4* rowp = xbase + ((size_t)((nt * 4 + bl) * 8 + sx)) * 1024;
            float4 a = rowp[(2 * k2) * 4 + fq];
            float4 cq = rowp[(2 * k2 + 1) * 4 + fq];
            #pragma unroll
            for (int e = 0; e < 4; ++e) {
                float va = (&a.x)[e], vb = (&cq.x)[e];
                __hip_bfloat16 ha = __float2bfloat16(va);
                __hip_bfloat16 hb = __float2bfloat16(vb);
                uint u = (uint)reinterpret_cast<ushort&>(ha) |
                         ((uint)reinterpret_cast<ushort&>(hb) << 16);
                int row = bl * 16 + fq * 4 + e;
                *reinterpret_cast<uint*>(reinterpret_cast<char*>(Xts) + row * 528 + k2 * 4) = u;
            }
        }
    }
    __syncthreads();

    const int lane = t & 63, wid = t >> 6;
    const int laneM = lane & 15, laneG = lane >> 4;
    const int wj0 = wid * 64;                   // wave's j base
    const int kmax = wj0 + 64;                  // triangle skip

    const char* XtsB = reinterpret_cast<const char*>(Xts);
    const char* WB = reinterpret_cast<const char*>(wforL);
    const int abyte = laneM * 528 + laneG * 16;

    // B element e (lane) for frag n, step kc: wfor[w00 + kc - 16n + e]
    const int w00 = 255 + diag - wj0 - laneM + 8 * laneG;
    const int s = (laneM - diag + 1) & 3;       // makes (w00+s) % 4 == 0
    const int bB = s * 674 + 2 * w00;           // byte base (incl. +s shift)

    f32x4 acc[4][4];
    #pragma unroll
    for (int m = 0; m < 4; ++m)
        #pragma unroll
        for (int n = 0; n < 4; ++n)
            acc[m][n] = (f32x4){0.0f, 0.0f, 0.0f, 0.0f};

    for (int kc = 0; kc < kmax; kc += 32) {
        FragAB af[4];
        #pragma unroll
        for (int m = 0; m < 4; ++m) {
            const int4 raw = *reinterpret_cast<const int4*>(XtsB + abyte + m * 8448 + kc * 2);
            af[m].i[0] = raw.x; af[m].i[1] = raw.y;
            af[m].i[2] = raw.z; af[m].i[3] = raw.w;
        }
        FragAB bf[4];
        #pragma unroll
        for (int n = 0; n < 4; ++n) {
            const char* p = WB + bB + kc * 2 - 32 * n;
            bf[n].l[0] = *reinterpret_cast<const unsigned long long*>(p);
            bf[n].l[1] = *reinterpret_cast<const unsigned long long*>(p + 8);
        }
        #pragma unroll
        for (int m = 0; m < 4; ++m)
            #pragma unroll
            for (int n = 0; n < 4; ++n)
                acc[m][n] = __builtin_amdgcn_mfma_f32_16x16x32_bf16(
                    af[m].v, bf[n].v, acc[m][n], 0, 0, 0);
    }

    // ---- epilogue: scale rows, nontemporal float4 stores; m outer / n inner
    // so each m emits a 4 KB-contiguous run over n ----
    #pragma unroll
    for (int m = 0; m < 4; ++m) {
        const int b_ = nt * 4 + m;
        float* obase = out + (((size_t)(b_ * 4 + h) * 8 + sx) * 8 + sy) * 4096
                       + laneG * 4;
        #pragma unroll
        for (int n = 0; n < 4; ++n) {
            const int j = wj0 + 16 * n + laneM;
            const float rt = rtab[j];
            f32x4 v = acc[m][n] * rt;
            __builtin_nontemporal_store(
                v, reinterpret_cast<f32x4*>(obase + (size_t)j * 16));
        }
    }
}

extern "C" void kernel_launch(void* const* d_in, const int* in_sizes, int n_in,
                              void* d_out, int out_size, void* d_ws, size_t ws_size,
                              hipStream_t stream) {
    const float* x    = (const float*)d_in[0];   // [16,8,256,16]
    const float* kern = (const float*)d_in[1];   // [4,8,8,256]
    float* out = (float*)d_out;                  // [16,4,8,8,256,16]

    k_fused<<<1024, 256, 0, stream>>>(x, kern, out);
}